// Round 7
// baseline (165.456 us; speedup 1.0000x reference)
//
#include <hip/hip_runtime.h>
#include <stdint.h>

typedef unsigned short ushort_t;
typedef unsigned int uint32;
typedef __attribute__((ext_vector_type(8))) short short8;
typedef __attribute__((ext_vector_type(4))) float f32x4;
typedef __attribute__((ext_vector_type(8))) float f32x8;
typedef __attribute__((ext_vector_type(2))) float f32x2;
typedef __attribute__((ext_vector_type(16))) float f32x16;
typedef __attribute__((ext_vector_type(4))) uint32 uint4v;

#define NSEQ 2048
#define BSZ 8
#define EMB 512
#define NHEAD 8
#define HDIM 64
#define MTOK (NSEQ*BSZ)      // 16384
#define NH_TOT (BSZ*NHEAD)   // 64
#define NT (NSEQ/64)         // 32 KV tiles

#define VMCNT0 asm volatile("s_waitcnt vmcnt(0)" ::: "memory")
#define VMCNT4 asm volatile("s_waitcnt vmcnt(4)" ::: "memory")
#define BAR __builtin_amdgcn_s_barrier()

__device__ __forceinline__ ushort_t f2bf(float f) {
  uint32_t u = __builtin_bit_cast(uint32_t, f);
  u += 0x7FFFu + ((u >> 16) & 1u);
  return (ushort_t)(u >> 16);
}
__device__ __forceinline__ float bf2f(ushort_t u) {
  uint32_t x = ((uint32_t)u) << 16;
  return __builtin_bit_cast(float, x);
}

__device__ __forceinline__ void gll16(const void* g, void* l) {
  __builtin_amdgcn_global_load_lds(
      (const __attribute__((address_space(1))) void*)g,
      (__attribute__((address_space(3))) void*)l, 16, 0, 0);
}

// swizzle slot for row r (8 slots of 16B within a 128B row)
__device__ __forceinline__ int SW(int r) { return (r & 7) ^ ((r >> 3) & 7); }

// tree-sum of two f32x16 (32 values) -> scalar
__device__ __forceinline__ float vsum32(f32x16 a, f32x16 b) {
  f32x16 s = a + b;
  f32x8 t8 = __builtin_shufflevector(s, s, 0,1,2,3,4,5,6,7)
           + __builtin_shufflevector(s, s, 8,9,10,11,12,13,14,15);
  f32x4 t4 = __builtin_shufflevector(t8, t8, 0,1,2,3)
           + __builtin_shufflevector(t8, t8, 4,5,6,7);
  f32x2 t2 = __builtin_shufflevector(t4, t4, 0,1)
           + __builtin_shufflevector(t4, t4, 2,3);
  return t2[0] + t2[1];
}

// ---------------- f32 -> bf16 convert (fused x3) ----------------
__global__ void cvt3(const float* __restrict__ a, ushort_t* __restrict__ oa, int na4,
                     const float* __restrict__ b, ushort_t* __restrict__ ob, int nb4,
                     const float* __restrict__ c, ushort_t* __restrict__ oc, int nc4) {
  int i = blockIdx.x * blockDim.x + threadIdx.x;
  const float* src; ushort_t* dst; int j = i;
  if (j < na4) { src = a; dst = oa; }
  else {
    j -= na4;
    if (j < nb4) { src = b; dst = ob; }
    else { j -= nb4; if (j >= nc4) return; src = c; dst = oc; }
  }
  float4 v = reinterpret_cast<const float4*>(src)[j];
  union { ushort_t u[4]; uint64_t q; } o;
  o.u[0] = f2bf(v.x); o.u[1] = f2bf(v.y); o.u[2] = f2bf(v.z); o.u[3] = f2bf(v.w);
  reinterpret_cast<uint64_t*>(dst)[j] = o.q;
}

// ---------------- GEMM: C[M,N] = A[M,K] * B[N,K]^T + bias ----------------
template<int MODE>
__global__ __launch_bounds__(256) void gemm_bt(
    const ushort_t* __restrict__ A, const ushort_t* __restrict__ B,
    const float* __restrict__ bias,
    float* __restrict__ Cf, ushort_t* __restrict__ Cq,
    int M, int N, int K)
{
  __shared__ __align__(16) ushort_t As[128*64];
  __shared__ __align__(16) ushort_t Bs[128*64];
  const int t = threadIdx.x;
  const int w = t >> 6, l = t & 63;
  const int tm = blockIdx.y * 128, tn = blockIdx.x * 128;
  const int wm = w >> 1, wn = w & 1;

  f32x4 acc[4][4] = {};

  for (int k0 = 0; k0 < K; k0 += 64) {
    #pragma unroll
    for (int j = 0; j < 4; ++j) {
      int row = j*32 + w*8 + (l >> 3);
      int cole = ((l & 7) * 8) ^ ((row & 7) << 3);
      const ushort_t* ga = A + (size_t)(tm + row) * K + k0 + cole;
      const ushort_t* gb = B + (size_t)(tn + row) * K + k0 + cole;
      gll16(ga, As + j*2048 + w*512 + l*8);
      gll16(gb, Bs + j*2048 + w*512 + l*8);
    }
    __syncthreads();
    #pragma unroll
    for (int kk = 0; kk < 2; ++kk) {
      short8 af[4], bfr[4];
      #pragma unroll
      for (int mi = 0; mi < 4; ++mi) {
        int row = wm*64 + mi*16 + (l & 15);
        int byte = row*128 + ((kk*64 + ((l >> 4) * 16)) ^ ((row & 7) << 4));
        af[mi] = *reinterpret_cast<const short8*>(reinterpret_cast<const char*>(As) + byte);
      }
      #pragma unroll
      for (int ni = 0; ni < 4; ++ni) {
        int row = wn*64 + ni*16 + (l & 15);
        int byte = row*128 + ((kk*64 + ((l >> 4) * 16)) ^ ((row & 7) << 4));
        bfr[ni] = *reinterpret_cast<const short8*>(reinterpret_cast<const char*>(Bs) + byte);
      }
      #pragma unroll
      for (int mi = 0; mi < 4; ++mi)
        #pragma unroll
        for (int ni = 0; ni < 4; ++ni)
          acc[mi][ni] = __builtin_amdgcn_mfma_f32_16x16x32_bf16(af[mi], bfr[ni], acc[mi][ni], 0, 0, 0);
    }
    __syncthreads();
  }

  #pragma unroll
  for (int mi = 0; mi < 4; ++mi) {
    #pragma unroll
    for (int ni = 0; ni < 4; ++ni) {
      #pragma unroll
      for (int r = 0; r < 4; ++r) {
        int row = tm + wm*64 + mi*16 + ((l >> 4) * 4) + r;
        int col = tn + wn*64 + ni*16 + (l & 15);
        float v = acc[mi][ni][r] + bias[col];
        if constexpr (MODE == 1) {
          Cf[(size_t)row * N + col] = v;
        } else {
          int w3 = col >> 9, hx = (col >> 6) & 7, hd = col & 63;
          int n = row >> 3, bb = row & 7;
          Cq[(size_t)w3 * ((size_t)NH_TOT * NSEQ * HDIM)
             + ((size_t)(bb * NHEAD + hx) * NSEQ + n) * HDIM + hd] = f2bf(v);
        }
      }
    }
  }
}

// ---------------- V transpose: [head][n][hd] -> [head][hd][n] ----------------
__global__ __launch_bounds__(256) void transpose_v(
    const ushort_t* __restrict__ V, ushort_t* __restrict__ VT)
{
  __shared__ __align__(16) ushort_t T[64*64];
  const int t = threadIdx.x;
  const int head = blockIdx.y;
  const int n0 = blockIdx.x * 64;
  const size_t base = (size_t)head * NSEQ * HDIM;
  const int r = t >> 3, c0 = (t & 7) * 8;

  short8 a = *reinterpret_cast<const short8*>(V + base + (size_t)(n0 + r) * HDIM + c0);
  short8 b = *reinterpret_cast<const short8*>(V + base + (size_t)(n0 + r + 32) * HDIM + c0);
  #pragma unroll
  for (int e = 0; e < 8; ++e) {
    int d = c0 + e; int sw = SW(d) << 4;
    *reinterpret_cast<ushort_t*>(reinterpret_cast<char*>(T) + d*128 + ((r*2) ^ sw)) = (ushort_t)a[e];
    *reinterpret_cast<ushort_t*>(reinterpret_cast<char*>(T) + d*128 + (((r+32)*2) ^ sw)) = (ushort_t)b[e];
  }
  __syncthreads();
  #pragma unroll
  for (int i = 0; i < 2; ++i) {
    int d = (t >> 3) + 32*i, ch = t & 7;
    short8 v = *reinterpret_cast<const short8*>(
        reinterpret_cast<const char*>(T) + d*128 + ((ch*16) ^ (SW(d) << 4)));
    *reinterpret_cast<short8*>(VT + (size_t)head * HDIM * NSEQ + (size_t)d * NSEQ + n0 + ch*8) = v;
  }
}

// ---------------- Flash attention ----------------
// 32 q/wave, 1024 blocks, 2-buffer LDS (32KB) -> 4 blocks/CU, counted vmcnt,
// no-max softmax, l via in-reg tree sum, setprio on MFMA clusters.
#define CSC 0.18033688011112042f   /* (1/8) * log2(e) */

__global__ __launch_bounds__(256, 4) void attn_fwd(
    const ushort_t* __restrict__ Qb, const ushort_t* __restrict__ Kb,
    const ushort_t* __restrict__ VTb, ushort_t* __restrict__ Ob)
{
  __shared__ __align__(16) ushort_t Ks[2][64*64];
  __shared__ __align__(16) ushort_t Vs[2][64*64];
  const int t = threadIdx.x, w = t >> 6, l = t & 63;
  const int lq = l & 31, h = l >> 5;
  // XCD-aware swizzle: each XCD owns 8 heads (16 q-tiles each)
  const int L = blockIdx.x + 16 * blockIdx.y;          // 0..1023
  const int Tid = (L & 7) * 128 + (L >> 3);
  const int bh = Tid >> 4, qt = Tid & 15;
  const int b = bh >> 3, hh = bh & 7;
  const size_t hbase  = (size_t)bh * NSEQ * HDIM;
  const size_t vtbase = (size_t)bh * HDIM * NSEQ;
  const int qbase = qt*128 + w*32;

  // Q B-fragments, pre-scaled by CSC
  short8 qreg[4];
  #pragma unroll
  for (int kd = 0; kd < 4; ++kd) {
    short8 raw = *reinterpret_cast<const short8*>(
        Qb + hbase + (size_t)(qbase + lq) * HDIM + kd*16 + h*8);
    short8 q;
    #pragma unroll
    for (int e = 0; e < 8; ++e)
      q[e] = (short)f2bf(bf2f((ushort_t)raw[e]) * CSC);
    qreg[kd] = q;
  }

  f32x16 Oacc[2] = {};
  float l_run = 0.f;

  // staging geometry
  const int srow = t >> 3;
  const int scol = (t & 7) * 8;
  const int c0 = scol ^ (SW(srow) << 3);
  const int c1 = scol ^ (SW(srow + 32) << 3);
  const ushort_t* Kg0 = Kb  + hbase  + (size_t)srow       * HDIM + c0;
  const ushort_t* Kg1 = Kb  + hbase  + (size_t)(srow+32)  * HDIM + c1;
  const ushort_t* Vg0 = VTb + vtbase + (size_t)srow       * NSEQ + c0;
  const ushort_t* Vg1 = VTb + vtbase + (size_t)(srow+32)  * NSEQ + c1;

  auto STAGE = [&](int bi, int kt) {
    size_t ko = (size_t)kt * 64 * HDIM;
    int    vo = kt * 64;
    gll16(Kg0 + ko, &Ks[bi][0]    + t*8);
    gll16(Kg1 + ko, &Ks[bi][2048] + t*8);
    gll16(Vg0 + vo, &Vs[bi][0]    + t*8);
    gll16(Vg1 + vo, &Vs[bi][2048] + t*8);
  };

  VMCNT0;            // drain Q loads so vmcnt counting below is exact
  STAGE(0, 0);       // 4 outstanding

  int cur = 0;
  #pragma unroll 1
  for (int kt = 0; kt < NT; ++kt) {
    if (kt + 1 < NT) { STAGE(cur ^ 1, kt + 1); VMCNT4; }  // kt done, kt+1 in flight
    else             { VMCNT0; }
    BAR;                                                   // buf[cur] ready for all

    const char* KsC = reinterpret_cast<const char*>(&Ks[cur][0]);
    const char* VsC = reinterpret_cast<const char*>(&Vs[cur][0]);

    // ---- batched K fragment loads ----
    short8 kf[2][4];
    #pragma unroll
    for (int rp = 0; rp < 2; ++rp) {
      int row = rp*32 + lq;
      int swr = SW(row) << 4;
      #pragma unroll
      for (int kd = 0; kd < 4; ++kd)
        kf[rp][kd] = *reinterpret_cast<const short8*>(
            KsC + row*128 + ((kd*32 + h*16) ^ swr));
    }

    // ---- S^T = K · (Q·CSC)^T ----
    f32x16 s0 = {}, s1 = {};
    __builtin_amdgcn_s_setprio(1);
    #pragma unroll
    for (int kd = 0; kd < 4; ++kd) {
      s0 = __builtin_amdgcn_mfma_f32_32x32x16_bf16(kf[0][kd], qreg[kd], s0, 0, 0, 0);
      s1 = __builtin_amdgcn_mfma_f32_32x32x16_bf16(kf[1][kd], qreg[kd], s1, 0, 0, 0);
    }
    __builtin_amdgcn_s_setprio(0);

    // ---- P = 2^S ----
    #pragma unroll
    for (int r = 0; r < 16; ++r) {
      s0[r] = __builtin_amdgcn_exp2f(s0[r]);
      s1[r] = __builtin_amdgcn_exp2f(s1[r]);
    }
    float ps = vsum32(s0, s1);
    ps += __shfl_xor(ps, 32);
    l_run += ps;

    // ---- pack P to bf16 (s0/s1 die here) ----
    uint32 w0[8], w1[8];
    #pragma unroll
    for (int i = 0; i < 8; ++i) {
      float a0 = s0[2*i], b0 = s0[2*i+1];
      float a1 = s1[2*i], b1 = s1[2*i+1];
      asm("v_cvt_pk_bf16_f32 %0, %1, %2" : "=v"(w0[i]) : "v"(a0), "v"(b0));
      asm("v_cvt_pk_bf16_f32 %0, %1, %2" : "=v"(w1[i]) : "v"(a1), "v"(b1));
    }

    // ---- batched V fragment loads ----
    short8 vf[2][4];
    #pragma unroll
    for (int dt = 0; dt < 2; ++dt) {
      int d = dt*32 + lq;
      int swd = SW(d) << 4;
      #pragma unroll
      for (int km = 0; km < 4; ++km)
        vf[dt][km] = *reinterpret_cast<const short8*>(
            VsC + d*128 + ((km*32 + h*16) ^ swd));
    }

    // ---- O += P V : build each P fragment via permlane pair, consume immediately ----
    __builtin_amdgcn_s_setprio(1);
    #pragma unroll
    for (int half = 0; half < 2; ++half) {
      #pragma unroll
      for (int sg = 0; sg < 2; ++sg) {
        int km = half*2 + sg;
        uint32 a, bb, c, d;
        if (half == 0) { a = w0[4*sg+0]; bb = w0[4*sg+2]; c = w0[4*sg+1]; d = w0[4*sg+3]; }
        else           { a = w1[4*sg+0]; bb = w1[4*sg+2]; c = w1[4*sg+1]; d = w1[4*sg+3]; }
        asm("v_permlane32_swap_b32 %0, %1" : "+v"(a), "+v"(bb));
        asm("v_permlane32_swap_b32 %0, %1" : "+v"(c), "+v"(d));
        uint4v u; u[0] = a; u[1] = c; u[2] = bb; u[3] = d;
        short8 paf = __builtin_bit_cast(short8, u);
        Oacc[0] = __builtin_amdgcn_mfma_f32_32x32x16_bf16(paf, vf[0][km], Oacc[0], 0, 0, 0);
        Oacc[1] = __builtin_amdgcn_mfma_f32_32x32x16_bf16(paf, vf[1][km], Oacc[1], 0, 0, 0);
      }
    }
    __builtin_amdgcn_s_setprio(0);

    BAR;              // all waves done reading buf[cur]; next iter may overwrite it
    cur ^= 1;
  }

  // ---- epilogue: O /= l ----
  float linv = __builtin_amdgcn_rcpf(l_run);
  #pragma unroll
  for (int r = 0; r < 16; ++r) {
    int qrow = (r & 3) + 8*(r >> 2) + 4*h;
    float li = __shfl(linv, qrow, 64);
    int n = qbase + qrow;
    #pragma unroll
    for (int dt = 0; dt < 2; ++dt) {
      int d = dt*32 + lq;
      Ob[((size_t)n * BSZ + b) * EMB + hh*64 + d] = f2bf(Oacc[dt][r] * li);
    }
  }
}

extern "C" void kernel_launch(void* const* d_in, const int* in_sizes, int n_in,
                              void* d_out, int out_size, void* d_ws, size_t ws_size,
                              hipStream_t stream) {
  (void)in_sizes; (void)n_in; (void)out_size; (void)ws_size;
  const float* seq  = (const float*)d_in[0];
  const float* Wqkv = (const float*)d_in[1];
  const float* bqkv = (const float*)d_in[2];
  const float* Wout = (const float*)d_in[3];
  const float* bout = (const float*)d_in[4];
  float* out = (float*)d_out;

  ushort_t* seq_bf  = (ushort_t*)d_ws;
  ushort_t* wqkv_bf = seq_bf  + (size_t)MTOK * EMB;
  ushort_t* wout_bf = wqkv_bf + (size_t)3 * EMB * EMB;
  ushort_t* qkvbuf  = wout_bf + (size_t)EMB * EMB;
  ushort_t* vtbuf   = qkvbuf  + (size_t)3 * NH_TOT * NSEQ * HDIM;
  // attn output aliases the V region (V is dead after transpose_v)
  ushort_t* attno   = qkvbuf  + (size_t)2 * NH_TOT * NSEQ * HDIM;

  const int na4 = MTOK*EMB/4, nb4 = 3*EMB*EMB/4, nc4 = EMB*EMB/4;
  cvt3<<<(na4+nb4+nc4 + 255)/256, 256, 0, stream>>>(
      seq, seq_bf, na4, Wqkv, wqkv_bf, nb4, Wout, wout_bf, nc4);

  gemm_bt<0><<<dim3(12, 128), 256, 0, stream>>>(seq_bf, wqkv_bf, bqkv, nullptr, qkvbuf,
                                                MTOK, 3*EMB, EMB);

  const ushort_t* Qb  = qkvbuf;
  const ushort_t* Kb  = qkvbuf + (size_t)NH_TOT * NSEQ * HDIM;
  const ushort_t* Vb  = Kb     + (size_t)NH_TOT * NSEQ * HDIM;

  transpose_v<<<dim3(32, 64), 256, 0, stream>>>(Vb, vtbuf);

  attn_fwd<<<dim3(16, 64), 256, 0, stream>>>(Qb, Kb, vtbuf, attno);

  gemm_bt<1><<<dim3(4, 128), 256, 0, stream>>>(attno, wout_bf, bout, out, nullptr,
                                               MTOK, EMB, EMB);
}